// Round 21
// baseline (1198.523 us; speedup 1.0000x reference)
//
#include <hip/hip_runtime.h>
#include <math.h>

namespace {
constexpr int kV = 12001;
constexpr int kE = 300;
constexpr int kEp = 320;   // padded K for i2h
constexpr int kR = 1024;
constexpr int kH = 512;
constexpr int kF = 2048;
constexpr int kB = 64;
constexpr int kT = 20;
constexpr int kL = 196;
constexpr int kNcat = 5 * kR + kH;   // 5632: [h2h | h2att]
constexpr int kKS = 4;               // K-split for gemm_sums (R17-proven)
constexpr int kNc2 = kH + kF;        // 2560: [p_att | itr-interleaved] cols
constexpr int kCombBlk = 20 * 98;    // 1960 comb blocks
constexpr int kI2hBlk  = 40 * 10;    // 400 i2h blocks
}

typedef __attribute__((ext_vector_type(8))) short short8;
typedef __attribute__((ext_vector_type(4))) float f32x4;

#define GLB_PTR(p) ((const __attribute__((address_space(1))) void*)(p))
#define LDS_PTR(p) ((__attribute__((address_space(3))) void*)(p))

__device__ __forceinline__ unsigned short f2bf(float f) {
    unsigned u = __builtin_bit_cast(unsigned, f);
    u = (u + 0x7fffu + ((u >> 16) & 1u)) >> 16;
    return (unsigned short)u;
}
__device__ __forceinline__ float bf2f(unsigned short h) {
    unsigned u = ((unsigned)h) << 16;
    return __builtin_bit_cast(float, u);
}
__device__ __forceinline__ float fast_tanh(float x) {
    x = fminf(15.f, fmaxf(-15.f, x));
    const float e = __expf(2.f * x);
    return (e - 1.f) / (e + 1.f);
}
__device__ __forceinline__ float fast_sig(float x) {
    return 1.f / (1.f + __expf(-x));
}

// bijective XCD-chunk swizzle (m204)
__device__ __forceinline__ int xcd_swizzle(int orig, int nwg) {
    const int q = nwg >> 3, r = nwg & 7;
    const int xcd = orig & 7, lo = orig >> 3;
    return (xcd < r ? xcd * (q + 1) : r * (q + 1) + (xcd - r) * q) + lo;
}

// ---------------------------------------------------------------------------
// One-shot conversion/pack/zero kernel.
// wcomb rows: 0-511 = ctx2att; 512+2r = a2c gate3 row r; 512+2r+1 = gate4 row r.
// ---------------------------------------------------------------------------
__global__ __launch_bounds__(256)
void conv_all_kernel(const float* __restrict__ af_in,  unsigned short* __restrict__ af_out,
                     const float* __restrict__ ctx_in,
                     const float* __restrict__ lg_in,  unsigned short* __restrict__ lg_out,
                     const float* __restrict__ h2h_in, unsigned short* __restrict__ h2h_out,
                     const float* __restrict__ h2a_in, unsigned short* __restrict__ h2a_out,
                     const float* __restrict__ a2c_in, unsigned short* __restrict__ wcomb_out,
                     const float* __restrict__ emb_in, unsigned short* __restrict__ emb_out,
                     const float* __restrict__ i2h_in, unsigned short* __restrict__ i2h_out,
                     unsigned short* __restrict__ hz_out, float* __restrict__ cb_out,
                     const float* __restrict__ ctxb_in, const float* __restrict__ a2cb_in,
                     float* __restrict__ biasc_out)
{
    constexpr int c0 = kB * kL * kF / 4;                 // af
    constexpr int c1 = c0 + kH * kF / 4;                 // ctx -> wcomb rows 0-511
    constexpr int c2 = c1 + kV * kR / 4;                 // logit
    constexpr int c3 = c2 + 5 * kR * kR / 4;             // h2h -> wcat
    constexpr int c4 = c3 + kH * kR / 4;                 // h2att -> wcat tail
    constexpr int c5 = c4 + 2 * kR * kF / 4;             // a2c -> wcomb interleaved
    constexpr int c6 = c5 + kV * 80;                     // embed pad
    constexpr int c7 = c6 + 5 * kR * 80;                 // i2h pad
    constexpr int c8 = c7 + kB * kR / 4;                 // h_zero
    constexpr int c9 = c8 + kB * kR / 4;                 // cbuf zero
    constexpr int c10 = c9 + kNc2 / 4;                   // bias_comb

    for (int i = blockIdx.x * 256 + threadIdx.x; i < c10; i += gridDim.x * 256) {
        if (i < c4) {
            const float* in; unsigned short* out; int l;
            if      (i < c0) { in = af_in;  out = af_out;    l = i; }
            else if (i < c1) { in = ctx_in; out = wcomb_out; l = i - c0; }
            else if (i < c2) { in = lg_in;  out = lg_out;    l = i - c1; }
            else if (i < c3) { in = h2h_in; out = h2h_out;   l = i - c2; }
            else             { in = h2a_in; out = h2a_out;   l = i - c3; }
            const float4 v = ((const float4*)in)[l];
            ushort4 o;
            o.x = f2bf(v.x); o.y = f2bf(v.y); o.z = f2bf(v.z); o.w = f2bf(v.w);
            ((ushort4*)out)[l] = o;
        } else if (i < c5) {
            // a2c row q -> wcomb row 512 + (q<kR ? 2q : 2(q-kR)+1)
            const int l = i - c4;
            const int q = l >> 9;                 // row (kF/4 = 512 groups)
            const int g = l & 511;                // col group
            const int irow = (q < kR) ? (kH + 2 * q) : (kH + 2 * (q - kR) + 1);
            const float4 v = ((const float4*)a2c_in)[l];
            ushort4 o;
            o.x = f2bf(v.x); o.y = f2bf(v.y); o.z = f2bf(v.z); o.w = f2bf(v.w);
            ((ushort4*)wcomb_out)[(size_t)irow * (kF / 4) + g] = o;
        } else if (i < c7) {
            const float* in; unsigned short* out; int l;
            if (i < c6) { in = emb_in; out = emb_out; l = i - c5; }
            else        { in = i2h_in; out = i2h_out; l = i - c6; }
            const int row = l / 80, c = l - row * 80;
            ushort4 o = make_ushort4(0, 0, 0, 0);
            if (c < 75) {
                const float4 v = *(const float4*)(in + (size_t)row * kE + c * 4);
                o.x = f2bf(v.x); o.y = f2bf(v.y); o.z = f2bf(v.z); o.w = f2bf(v.w);
            }
            *(ushort4*)(out + (size_t)row * kEp + c * 4) = o;
        } else if (i < c8) {
            ((ushort4*)hz_out)[i - c7] = make_ushort4(0, 0, 0, 0);
        } else if (i < c9) {
            ((float4*)cb_out)[i - c8] = make_float4(0.f, 0.f, 0.f, 0.f);
        } else {
            const int l = i - c9;   // float4 group of bias_comb (640 groups)
            float4 v;
            if (l < kH / 4) {
                v = ((const float4*)ctxb_in)[l];
            } else {
                const int j0 = (l - kH / 4) * 4;
                float t[4];
                #pragma unroll
                for (int p = 0; p < 4; ++p) {
                    const int j = j0 + p;
                    const int r = j >> 1;
                    t[p] = a2cb_in[(j & 1) * kR + r];
                }
                v = make_float4(t[0], t[1], t[2], t[3]);
            }
            ((float4*)biasc_out)[l] = v;
        }
    }
}

// ---------------------------------------------------------------------------
// DUAL front GEMM: one dispatch runs comb (1960 blocks) + i2h (400 blocks).
// Runtime-parameterized body, bf16 out, width-16 global_load_lds staging.
// ---------------------------------------------------------------------------
__global__ __launch_bounds__(256)
void gemm_dual_kernel(const unsigned short* __restrict__ af_bf,
                      const unsigned short* __restrict__ wcomb_bf,
                      const float* __restrict__ bias_comb,
                      unsigned short* __restrict__ comb_bf,
                      const unsigned short* __restrict__ embed_bf,
                      const unsigned short* __restrict__ i2h_bf,
                      const float* __restrict__ i2h_b,
                      unsigned short* __restrict__ i2h_pre_bf,
                      const int* __restrict__ seq)
{
    __shared__ __align__(16) unsigned short sA[128 * 32];
    __shared__ __align__(16) unsigned short sW[128 * 32];
    const int tid = threadIdx.x;
    const int swz = xcd_swizzle(blockIdx.x, kCombBlk + kI2hBlk);

    const unsigned short* Ah; const unsigned short* Wh;
    const float* bias; unsigned short* Cp;
    const int* ridx;
    int lda, ldw, ldc, N, K, m0, n0;
    if (swz < kCombBlk) {
        const int bx = swz % 20, by = swz / 20;
        Ah = af_bf; lda = kF; Wh = wcomb_bf; ldw = kF; bias = bias_comb;
        Cp = comb_bf; ldc = kNc2; N = kNc2; K = kF;
        m0 = by * 128; n0 = bx * 128; ridx = nullptr;
    } else {
        const int s = swz - kCombBlk;
        const int bx = s % 40, by = s / 40;
        Ah = embed_bf; lda = kEp; Wh = i2h_bf; ldw = kEp; bias = i2h_b;
        Cp = i2h_pre_bf; ldc = 5 * kR; N = 5 * kR; K = kEp;
        m0 = by * 128; n0 = bx * 128; ridx = seq;
    }

    const int wave = tid >> 6, lane = tid & 63;
    const int wm = wave >> 1, wn = wave & 1;
    const int lrow = lane & 15, lkg = lane >> 4;
    const int rsub   = lane >> 2;
    const int cchunk = (lane & 3) * 8;

    f32x4 acc[4][4];
    #pragma unroll
    for (int mi = 0; mi < 4; ++mi)
        #pragma unroll
        for (int ni = 0; ni < 4; ++ni)
            acc[mi][ni] = (f32x4){0.f, 0.f, 0.f, 0.f};

    for (int k0 = 0; k0 < K; k0 += 32) {
        #pragma unroll
        for (int j = 0; j < 2; ++j) {
            const int mrow = m0 + wave * 32 + j * 16 + rsub;
            const int row = ridx ? ridx[mrow] : mrow;
            __builtin_amdgcn_global_load_lds(
                GLB_PTR(Ah + (size_t)row * lda + k0 + cchunk),
                LDS_PTR(sA + wave * 1024 + j * 512), 16, 0, 0);
        }
        #pragma unroll
        for (int j = 0; j < 2; ++j) {
            const int n = n0 + wave * 32 + j * 16 + rsub;
            __builtin_amdgcn_global_load_lds(
                GLB_PTR(Wh + (size_t)n * ldw + k0 + cchunk),
                LDS_PTR(sW + wave * 1024 + j * 512), 16, 0, 0);
        }
        __syncthreads();

        short8 af[4], wf[4];
        #pragma unroll
        for (int mi = 0; mi < 4; ++mi)
            af[mi] = *(const short8*)(sA + (wm * 64 + mi * 16 + lrow) * 32 + lkg * 8);
        #pragma unroll
        for (int ni = 0; ni < 4; ++ni)
            wf[ni] = *(const short8*)(sW + (wn * 64 + ni * 16 + lrow) * 32 + lkg * 8);
        #pragma unroll
        for (int mi = 0; mi < 4; ++mi)
            #pragma unroll
            for (int ni = 0; ni < 4; ++ni)
                acc[mi][ni] = __builtin_amdgcn_mfma_f32_16x16x32_bf16(af[mi], wf[ni], acc[mi][ni], 0, 0, 0);
        __syncthreads();
    }

    // epilogue: row = (lane>>4)*4 + reg, col = lane&15 (m89-verified layout)
    #pragma unroll
    for (int mi = 0; mi < 4; ++mi) {
        const int mbase = m0 + wm * 64 + mi * 16 + lkg * 4;
        #pragma unroll
        for (int ni = 0; ni < 4; ++ni) {
            const int n = n0 + wn * 64 + ni * 16 + lrow;
            if (n >= N) continue;
            const float bb = bias[n];
            #pragma unroll
            for (int r = 0; r < 4; ++r) {
                const int m = mbase + r;
                Cp[(size_t)m * ldc + n] = f2bf(acc[mi][ni][r] + bb);
            }
        }
    }
}

// ---------------------------------------------------------------------------
// Pure-bf16 MFMA GEMM (fp32 out), glds staging, XCD-swizzled — logits.
// ---------------------------------------------------------------------------
__global__ __launch_bounds__(256)
void gemm_glds_kernel(const unsigned short* __restrict__ Ah, int lda,
                      const unsigned short* __restrict__ Wh, int ldw,
                      const float* __restrict__ bias,
                      float* __restrict__ Cp, int ldc,
                      int M, int N, int K,
                      int nbx, int nby)
{
    __shared__ __align__(16) unsigned short sA[128 * 32];
    __shared__ __align__(16) unsigned short sW[128 * 32];
    const int tid = threadIdx.x;
    const int swz = xcd_swizzle(blockIdx.x, nbx * nby);
    const int by = swz % nby, bx = swz / nby;   // by fastest (share W panels)
    const int m0 = by * 128;
    const int n0 = bx * 128;
    const int wave = tid >> 6, lane = tid & 63;
    const int wm = wave >> 1, wn = wave & 1;
    const int lrow = lane & 15, lkg = lane >> 4;

    const int rsub   = lane >> 2;
    const int cchunk = (lane & 3) * 8;

    f32x4 acc[4][4];
    #pragma unroll
    for (int mi = 0; mi < 4; ++mi)
        #pragma unroll
        for (int ni = 0; ni < 4; ++ni)
            acc[mi][ni] = (f32x4){0.f, 0.f, 0.f, 0.f};

    for (int k0 = 0; k0 < K; k0 += 32) {
        #pragma unroll
        for (int j = 0; j < 2; ++j) {
            const int mrow = m0 + wave * 32 + j * 16 + rsub;
            __builtin_amdgcn_global_load_lds(
                GLB_PTR(Ah + (size_t)mrow * lda + k0 + cchunk),
                LDS_PTR(sA + wave * 1024 + j * 512), 16, 0, 0);
        }
        #pragma unroll
        for (int j = 0; j < 2; ++j) {
            const int n = n0 + wave * 32 + j * 16 + rsub;
            __builtin_amdgcn_global_load_lds(
                GLB_PTR(Wh + (size_t)n * ldw + k0 + cchunk),
                LDS_PTR(sW + wave * 1024 + j * 512), 16, 0, 0);
        }
        __syncthreads();

        short8 af[4], wf[4];
        #pragma unroll
        for (int mi = 0; mi < 4; ++mi)
            af[mi] = *(const short8*)(sA + (wm * 64 + mi * 16 + lrow) * 32 + lkg * 8);
        #pragma unroll
        for (int ni = 0; ni < 4; ++ni)
            wf[ni] = *(const short8*)(sW + (wn * 64 + ni * 16 + lrow) * 32 + lkg * 8);
        #pragma unroll
        for (int mi = 0; mi < 4; ++mi)
            #pragma unroll
            for (int ni = 0; ni < 4; ++ni)
                acc[mi][ni] = __builtin_amdgcn_mfma_f32_16x16x32_bf16(af[mi], wf[ni], acc[mi][ni], 0, 0, 0);
        __syncthreads();
    }

    #pragma unroll
    for (int mi = 0; mi < 4; ++mi) {
        const int mbase = m0 + wm * 64 + mi * 16 + lkg * 4;
        #pragma unroll
        for (int ni = 0; ni < 4; ++ni) {
            const int n = n0 + wn * 64 + ni * 16 + lrow;
            if (n >= N) continue;
            const float bb = bias[n];
            #pragma unroll
            for (int r = 0; r < 4; ++r) {
                const int m = mbase + r;
                Cp[(size_t)m * ldc + n] = acc[mi][ni][r] + bb;
            }
        }
    }
}

// ---------------------------------------------------------------------------
// Small-M sums GEMM with glds staging: part[ks][64][N] = A(64xK)@W(NxK).T
// ---------------------------------------------------------------------------
__global__ __launch_bounds__(256)
void gemm_sums_kernel(const unsigned short* __restrict__ A, int lda,
                      const unsigned short* __restrict__ W, int ldw,
                      float* __restrict__ part, int N, int Kblk)
{
    __shared__ __align__(16) unsigned short sA[64 * 32];
    __shared__ __align__(16) unsigned short sW[64 * 32];
    const int tid = threadIdx.x;
    const int n0 = blockIdx.x * 64;
    const int ks = blockIdx.y;
    const int kbeg = ks * Kblk;
    const int wave = tid >> 6, lane = tid & 63;
    const int lrow = lane & 15, lkg = lane >> 4;
    const int rsub   = lane >> 2;
    const int cchunk = (lane & 3) * 8;

    f32x4 acc[4];
    #pragma unroll
    for (int mi = 0; mi < 4; ++mi) acc[mi] = (f32x4){0.f, 0.f, 0.f, 0.f};

    for (int k0 = kbeg; k0 < kbeg + Kblk; k0 += 32) {
        __builtin_amdgcn_global_load_lds(
            GLB_PTR(A + (size_t)(wave * 16 + rsub) * lda + k0 + cchunk),
            LDS_PTR(sA + wave * 512), 16, 0, 0);
        __builtin_amdgcn_global_load_lds(
            GLB_PTR(W + (size_t)(n0 + wave * 16 + rsub) * ldw + k0 + cchunk),
            LDS_PTR(sW + wave * 512), 16, 0, 0);
        __syncthreads();
        const short8 wf = *(const short8*)(sW + (wave * 16 + lrow) * 32 + lkg * 8);
        #pragma unroll
        for (int mi = 0; mi < 4; ++mi) {
            const short8 af = *(const short8*)(sA + (mi * 16 + lrow) * 32 + lkg * 8);
            acc[mi] = __builtin_amdgcn_mfma_f32_16x16x32_bf16(af, wf, acc[mi], 0, 0, 0);
        }
        __syncthreads();
    }

    float* po = part + (size_t)ks * 64 * N;
    const int n = n0 + wave * 16 + lrow;
    #pragma unroll
    for (int mi = 0; mi < 4; ++mi)
        #pragma unroll
        for (int rr = 0; rr < 4; ++rr)
            po[(size_t)(mi * 16 + lkg * 4 + rr) * N + n] = acc[mi][rr];
}

// ---------------------------------------------------------------------------
// Step kernel (512 thr): e + softmax + l-split INTERLEAVED readout + gates.
// grid (64 b, 4 fc): same-b blocks share one XCD (64 % 8 == 0).
// ---------------------------------------------------------------------------
__global__ __launch_bounds__(512)
void att_step_kernel(const float* __restrict__ part56,
                     const float* __restrict__ h2att_b,
                     const unsigned short* __restrict__ comb_bf,
                     const float* __restrict__ alpha_w,
                     const unsigned short* __restrict__ i2h_pre_bf,
                     const float* __restrict__ h2h_b,
                     float* __restrict__ cbuf,
                     unsigned short* __restrict__ h_all_bf,
                     int t)
{
    const int b = blockIdx.x, fc = blockIdx.y;
    const int tid = threadIdx.x;
    const int wave = tid >> 6, lane = tid & 63;
    __shared__ float ahT[8][64];
    __shared__ float awT[8][64];
    __shared__ float esm[kL];
    __shared__ float wsm[kL];
    __shared__ float red2[2];

    if (tid < kH) {
        const size_t base = (size_t)b * kNcat + 5 * kR + tid;
        float v = h2att_b[tid];
        #pragma unroll
        for (int s = 0; s < kKS; ++s) v += part56[(size_t)s * 64 * kNcat + base];
        ahT[tid & 7][tid >> 3] = v;
        awT[tid & 7][tid >> 3] = alpha_w[tid];
    }
    __syncthreads();

    // e: 8 waves, wave handles l = wave, wave+8, ...
    for (int l = wave; l < kL; l += 8) {
        const short8 pv = *(const short8*)(comb_bf + ((size_t)b * kL + l) * kNc2 + lane * 8);
        float a = 0.f;
        #pragma unroll
        for (int j = 0; j < 8; ++j)
            a += fast_tanh(bf2f(((const unsigned short*)&pv)[j]) + ahT[j][lane]) * awT[j][lane];
        #pragma unroll
        for (int off = 32; off; off >>= 1) a += __shfl_xor(a, off, 64);
        if (lane == 0) esm[l] = a;
    }
    __syncthreads();

    if (wave == 0) {
        float m = -1e30f;
        for (int l = lane; l < kL; l += 64) m = fmaxf(m, esm[l]);
        #pragma unroll
        for (int off = 32; off; off >>= 1) m = fmaxf(m, __shfl_xor(m, off, 64));
        float ssum = 0.f;
        for (int l = lane; l < kL; l += 64) ssum += __expf(esm[l] - m);
        #pragma unroll
        for (int off = 32; off; off >>= 1) ssum += __shfl_xor(ssum, off, 64);
        if (lane == 0) { red2[0] = m; red2[1] = 1.f / ssum; }
    }
    __syncthreads();
    if (tid < kL) wsm[tid] = __expf(esm[tid] - red2[0]) * red2[1];
    __syncthreads();

    // l-split interleaved readout: one ushort2 per l = (gate3, gate4)
    const int r = fc * 256 + (tid >> 1);
    const int l0 = (tid & 1) * 98;
    float s3 = 0.f, s4 = 0.f;
    const unsigned short* base = comb_bf + ((size_t)b * kL + l0) * kNc2 + kH + 2 * r;
    #pragma unroll 7
    for (int li = 0; li < 98; ++li) {
        const ushort2 v = *(const ushort2*)(base + (size_t)li * kNc2);
        const float wl = wsm[l0 + li];
        s3 += wl * bf2f(v.x);
        s4 += wl * bf2f(v.y);
    }
    s3 += __shfl_xor(s3, 1, 64);
    s4 += __shfl_xor(s4, 1, 64);

    if ((tid & 1) == 0) {
        const unsigned short* ib = i2h_pre_bf + (size_t)(b * kT + t) * (5 * kR);
        float S0 = bf2f(ib[r])          + h2h_b[r];
        float S1 = bf2f(ib[kR + r])     + h2h_b[kR + r];
        float S2 = bf2f(ib[2 * kR + r]) + h2h_b[2 * kR + r];
        float S3 = bf2f(ib[3 * kR + r]) + h2h_b[3 * kR + r] + s3;
        float S4 = bf2f(ib[4 * kR + r]) + h2h_b[4 * kR + r] + s4;
        #pragma unroll
        for (int s = 0; s < kKS; ++s) {
            const float* p = part56 + (size_t)s * 64 * kNcat + (size_t)b * kNcat;
            S0 += p[r];
            S1 += p[kR + r];
            S2 += p[2 * kR + r];
            S3 += p[3 * kR + r];
            S4 += p[4 * kR + r];
        }

        const float ing = fast_sig(S0);
        const float fg  = fast_sig(S1);
        const float og  = fast_sig(S2);
        const float gg  = fmaxf(S3, S4);
        const int idx = b * kR + r;
        const float nc = fg * cbuf[idx] + ing * gg;
        const float nh = og * fast_tanh(nc);
        cbuf[idx] = nc;
        h_all_bf[(size_t)(b * kT + t) * kR + r] = f2bf(nh);
    }
}

// ---------------------------------------------------------------------------
// in-place log_softmax over V; one block per row, 512 thr, float4 loads.
// ---------------------------------------------------------------------------
__global__ __launch_bounds__(512)
void log_softmax_kernel(float* __restrict__ out)
{
    __shared__ float mred[512];
    __shared__ float sred[512];
    const int tid = threadIdx.x;
    float* row = out + (size_t)blockIdx.x * kV;

    float m = -1e30f, s = 0.f;
    for (int g = tid; g < 3000; g += 512) {
        const float4 x4 = ((const float4*)row)[g];
        const float* x = (const float*)&x4;
        #pragma unroll
        for (int j = 0; j < 4; ++j) {
            const float x1 = x[j];
            if (x1 > m) { s = s * __expf(m - x1) + 1.f; m = x1; }
            else          s += __expf(x1 - m);
        }
    }
    if (tid == 0) {
        const float x1 = row[12000];
        if (x1 > m) { s = s * __expf(m - x1) + 1.f; m = x1; }
        else          s += __expf(x1 - m);
    }
    mred[tid] = m; sred[tid] = s; __syncthreads();
    for (int st = 256; st > 0; st >>= 1) {
        if (tid < st) {
            const float m2 = mred[tid + st], s2 = sred[tid + st];
            const float M = fmaxf(mred[tid], m2);
            sred[tid] = sred[tid] * __expf(mred[tid] - M) + s2 * __expf(m2 - M);
            mred[tid] = M;
        }
        __syncthreads();
    }
    const float ls = mred[0] + logf(sred[0]);
    for (int g = tid; g < 3000; g += 512) {
        float4 x4 = ((const float4*)row)[g];
        x4.x -= ls; x4.y -= ls; x4.z -= ls; x4.w -= ls;
        ((float4*)row)[g] = x4;
    }
    if (tid == 0) row[12000] -= ls;
}

extern "C" void kernel_launch(void* const* d_in, const int* in_sizes, int n_in,
                              void* d_out, int out_size, void* d_ws, size_t ws_size,
                              hipStream_t stream)
{
    const int*   seq       = (const int*)  d_in[0];
    const float* att_feats = (const float*)d_in[1];
    const float* embed_w   = (const float*)d_in[2];
    const float* ctx2att_w = (const float*)d_in[3];
    const float* ctx2att_b = (const float*)d_in[4];
    const float* h2att_w   = (const float*)d_in[5];
    const float* h2att_b   = (const float*)d_in[6];
    const float* alpha_w   = (const float*)d_in[7];
    const float* i2h_w     = (const float*)d_in[9];
    const float* i2h_b     = (const float*)d_in[10];
    const float* h2h_w     = (const float*)d_in[11];
    const float* h2h_b     = (const float*)d_in[12];
    const float* a2c_w     = (const float*)d_in[13];
    const float* a2c_b     = (const float*)d_in[14];
    const float* logit_w   = (const float*)d_in[15];
    const float* logit_b   = (const float*)d_in[16];
    float* out = (float*)d_out;

    float* ws = (float*)d_ws;
    size_t off = 0;
    auto alloc = [&](size_t nf) { float* p = ws + off; off += (nf + 3) & ~(size_t)3; return p; };

    unsigned short* af_bf      = (unsigned short*)alloc((size_t)kB * kL * kF / 2);   // 51 MB
    unsigned short* comb_bf    = (unsigned short*)alloc((size_t)kB * kL * kNc2 / 2); // 61.6 MB
    unsigned short* logit_hi   = (unsigned short*)alloc((size_t)kV * kR / 2);
    unsigned short* embed_bf   = (unsigned short*)alloc((size_t)kV * kEp / 2);
    unsigned short* i2h_bf     = (unsigned short*)alloc((size_t)5 * kR * kEp / 2);
    unsigned short* wcat_bf    = (unsigned short*)alloc((size_t)kNcat * kR / 2);     // 11.5 MB
    unsigned short* wcomb_bf   = (unsigned short*)alloc((size_t)kNc2 * kF / 2);      // 10.5 MB
    unsigned short* h_all_bf   = (unsigned short*)alloc((size_t)kB * kT * kR / 2);
    unsigned short* h_zero_bf  = (unsigned short*)alloc((size_t)kB * kR / 2);
    unsigned short* i2h_pre_bf = (unsigned short*)alloc((size_t)kB * kT * 5 * kR / 2); // 13 MB
    float* bias_comb = alloc((size_t)kNc2);
    float* part56    = alloc((size_t)kKS * kB * kNcat);  // 5.8 MB
    float* cbuf      = alloc((size_t)kB * kR);

    // all conversions + packs + zero-fills in ONE launch
    conv_all_kernel<<<4096, 256, 0, stream>>>(
        att_feats, af_bf, ctx2att_w, logit_w, logit_hi,
        h2h_w, wcat_bf, h2att_w, wcat_bf + (size_t)5 * kR * kR,
        a2c_w, wcomb_bf, embed_w, embed_bf, i2h_w, i2h_bf,
        h_zero_bf, cbuf, ctx2att_b, a2c_b, bias_comb);

    // comb + i2h_pre GEMMs fused into ONE dispatch (independent sub-grids)
    gemm_dual_kernel<<<dim3(kCombBlk + kI2hBlk), 256, 0, stream>>>(
        af_bf, wcomb_bf, bias_comb, comb_bf,
        embed_bf, i2h_bf, i2h_b, i2h_pre_bf, seq);

    // 20-step recurrence: 2 launches per step
    for (int t = 0; t < kT; ++t) {
        const unsigned short* h_prev = (t == 0) ? h_zero_bf : (h_all_bf + (size_t)(t - 1) * kR);
        const int lda_h = (t == 0) ? kR : kT * kR;

        // part56 = h_prev @ [h2h | h2att].T   (64 x 5632, K=1024, ks=4)
        gemm_sums_kernel<<<dim3(kNcat / 64, kKS), 256, 0, stream>>>(
            h_prev, lda_h, wcat_bf, kR, part56, kNcat, kR / kKS);

        att_step_kernel<<<dim3(kB, 4), 512, 0, stream>>>(
            part56, h2att_b, comb_bf, alpha_w, i2h_pre_bf, h2h_b,
            cbuf, h_all_bf, t);
    }

    // logits = h_all @ logit_w.T + b -> out fp32  (1280 x 12001, K=1024)
    gemm_glds_kernel<<<dim3(94 * 10), 256, 0, stream>>>(
        h_all_bf, kR, logit_hi, kR, logit_b, out, kV, kB * kT, kV, kR,
        94, 10);

    log_softmax_kernel<<<dim3(kB * kT), 512, 0, stream>>>(out);
}

// Round 22
// 1139.833 us; speedup vs baseline: 1.0515x; 1.0515x over previous
//
#include <hip/hip_runtime.h>
#include <math.h>

namespace {
constexpr int kV = 12001;
constexpr int kE = 300;
constexpr int kEp = 320;   // padded K for i2h
constexpr int kR = 1024;
constexpr int kH = 512;
constexpr int kF = 2048;
constexpr int kB = 64;
constexpr int kT = 20;
constexpr int kL = 196;
constexpr int kNcat = 5 * kR + kH;   // 5632: [h2h | h2att]
constexpr int kKS = 4;               // K-split for gemm_sums (R17-proven)
constexpr int kNc2 = kH + kF;        // 2560: [p_att | itr-interleaved] cols
}

typedef __attribute__((ext_vector_type(8))) short short8;
typedef __attribute__((ext_vector_type(4))) float f32x4;

#define GLB_PTR(p) ((const __attribute__((address_space(1))) void*)(p))
#define LDS_PTR(p) ((__attribute__((address_space(3))) void*)(p))

__device__ __forceinline__ unsigned short f2bf(float f) {
    unsigned u = __builtin_bit_cast(unsigned, f);
    u = (u + 0x7fffu + ((u >> 16) & 1u)) >> 16;
    return (unsigned short)u;
}
__device__ __forceinline__ float bf2f(unsigned short h) {
    unsigned u = ((unsigned)h) << 16;
    return __builtin_bit_cast(float, u);
}
__device__ __forceinline__ float fast_tanh(float x) {
    x = fminf(15.f, fmaxf(-15.f, x));
    const float e = __expf(2.f * x);
    return (e - 1.f) / (e + 1.f);
}
__device__ __forceinline__ float fast_sig(float x) {
    return 1.f / (1.f + __expf(-x));
}

// bijective XCD-chunk swizzle (m204)
__device__ __forceinline__ int xcd_swizzle(int orig, int nwg) {
    const int q = nwg >> 3, r = nwg & 7;
    const int xcd = orig & 7, lo = orig >> 3;
    return (xcd < r ? xcd * (q + 1) : r * (q + 1) + (xcd - r) * q) + lo;
}

// ---------------------------------------------------------------------------
// One-shot conversion/pack/zero kernel.
// wcomb rows: 0-511 = ctx2att; 512+2r = a2c gate3 row r; 512+2r+1 = gate4 row r.
// ---------------------------------------------------------------------------
__global__ __launch_bounds__(256)
void conv_all_kernel(const float* __restrict__ af_in,  unsigned short* __restrict__ af_out,
                     const float* __restrict__ ctx_in,
                     const float* __restrict__ lg_in,  unsigned short* __restrict__ lg_out,
                     const float* __restrict__ h2h_in, unsigned short* __restrict__ h2h_out,
                     const float* __restrict__ h2a_in, unsigned short* __restrict__ h2a_out,
                     const float* __restrict__ a2c_in, unsigned short* __restrict__ wcomb_out,
                     const float* __restrict__ emb_in, unsigned short* __restrict__ emb_out,
                     const float* __restrict__ i2h_in, unsigned short* __restrict__ i2h_out,
                     unsigned short* __restrict__ hz_out, float* __restrict__ cb_out,
                     const float* __restrict__ ctxb_in, const float* __restrict__ a2cb_in,
                     float* __restrict__ biasc_out)
{
    constexpr int c0 = kB * kL * kF / 4;                 // af
    constexpr int c1 = c0 + kH * kF / 4;                 // ctx -> wcomb rows 0-511
    constexpr int c2 = c1 + kV * kR / 4;                 // logit
    constexpr int c3 = c2 + 5 * kR * kR / 4;             // h2h -> wcat
    constexpr int c4 = c3 + kH * kR / 4;                 // h2att -> wcat tail
    constexpr int c5 = c4 + 2 * kR * kF / 4;             // a2c -> wcomb interleaved
    constexpr int c6 = c5 + kV * 80;                     // embed pad
    constexpr int c7 = c6 + 5 * kR * 80;                 // i2h pad
    constexpr int c8 = c7 + kB * kR / 4;                 // h_zero
    constexpr int c9 = c8 + kB * kR / 4;                 // cbuf zero
    constexpr int c10 = c9 + kNc2 / 4;                   // bias_comb

    for (int i = blockIdx.x * 256 + threadIdx.x; i < c10; i += gridDim.x * 256) {
        if (i < c4) {
            const float* in; unsigned short* out; int l;
            if      (i < c0) { in = af_in;  out = af_out;    l = i; }
            else if (i < c1) { in = ctx_in; out = wcomb_out; l = i - c0; }
            else if (i < c2) { in = lg_in;  out = lg_out;    l = i - c1; }
            else if (i < c3) { in = h2h_in; out = h2h_out;   l = i - c2; }
            else             { in = h2a_in; out = h2a_out;   l = i - c3; }
            const float4 v = ((const float4*)in)[l];
            ushort4 o;
            o.x = f2bf(v.x); o.y = f2bf(v.y); o.z = f2bf(v.z); o.w = f2bf(v.w);
            ((ushort4*)out)[l] = o;
        } else if (i < c5) {
            // a2c row q -> wcomb row 512 + (q<kR ? 2q : 2(q-kR)+1)
            const int l = i - c4;
            const int q = l >> 9;                 // row (kF/4 = 512 groups)
            const int g = l & 511;                // col group
            const int irow = (q < kR) ? (kH + 2 * q) : (kH + 2 * (q - kR) + 1);
            const float4 v = ((const float4*)a2c_in)[l];
            ushort4 o;
            o.x = f2bf(v.x); o.y = f2bf(v.y); o.z = f2bf(v.z); o.w = f2bf(v.w);
            ((ushort4*)wcomb_out)[(size_t)irow * (kF / 4) + g] = o;
        } else if (i < c7) {
            const float* in; unsigned short* out; int l;
            if (i < c6) { in = emb_in; out = emb_out; l = i - c5; }
            else        { in = i2h_in; out = i2h_out; l = i - c6; }
            const int row = l / 80, c = l - row * 80;
            ushort4 o = make_ushort4(0, 0, 0, 0);
            if (c < 75) {
                const float4 v = *(const float4*)(in + (size_t)row * kE + c * 4);
                o.x = f2bf(v.x); o.y = f2bf(v.y); o.z = f2bf(v.z); o.w = f2bf(v.w);
            }
            *(ushort4*)(out + (size_t)row * kEp + c * 4) = o;
        } else if (i < c8) {
            ((ushort4*)hz_out)[i - c7] = make_ushort4(0, 0, 0, 0);
        } else if (i < c9) {
            ((float4*)cb_out)[i - c8] = make_float4(0.f, 0.f, 0.f, 0.f);
        } else {
            const int l = i - c9;   // float4 group of bias_comb (640 groups)
            float4 v;
            if (l < kH / 4) {
                v = ((const float4*)ctxb_in)[l];
            } else {
                const int j0 = (l - kH / 4) * 4;
                float t[4];
                #pragma unroll
                for (int p = 0; p < 4; ++p) {
                    const int j = j0 + p;
                    const int r = j >> 1;
                    t[p] = a2cb_in[(j & 1) * kR + r];
                }
                v = make_float4(t[0], t[1], t[2], t[3]);
            }
            ((float4*)biasc_out)[l] = v;
        }
    }
}

// ---------------------------------------------------------------------------
// Pure-bf16 MFMA GEMM, width-16 global_load_lds staging, XCD-swizzled 1D grid.
// ---------------------------------------------------------------------------
template<bool OUT_BF16, bool GATHER>
__global__ __launch_bounds__(256)
void gemm_glds_kernel(const unsigned short* __restrict__ Ah, int lda,
                      const unsigned short* __restrict__ Wh, int ldw,
                      const float* __restrict__ bias,
                      void* __restrict__ Cp, int ldc,
                      int M, int N, int K,
                      const int* __restrict__ ridx,
                      int nbx, int nby, int nfirst)
{
    __shared__ __align__(16) unsigned short sA[128 * 32];
    __shared__ __align__(16) unsigned short sW[128 * 32];
    const int tid = threadIdx.x;
    const int swz = xcd_swizzle(blockIdx.x, nbx * nby);
    int bx, by;
    if (nfirst) { bx = swz % nbx; by = swz / nbx; }
    else        { by = swz % nby; bx = swz / nby; }
    const int m0 = by * 128;
    const int n0 = bx * 128;
    const int wave = tid >> 6, lane = tid & 63;
    const int wm = wave >> 1, wn = wave & 1;
    const int lrow = lane & 15, lkg = lane >> 4;

    const int rsub   = lane >> 2;
    const int cchunk = (lane & 3) * 8;

    f32x4 acc[4][4];
    #pragma unroll
    for (int mi = 0; mi < 4; ++mi)
        #pragma unroll
        for (int ni = 0; ni < 4; ++ni)
            acc[mi][ni] = (f32x4){0.f, 0.f, 0.f, 0.f};

    for (int k0 = 0; k0 < K; k0 += 32) {
        #pragma unroll
        for (int j = 0; j < 2; ++j) {
            const int mrow = m0 + wave * 32 + j * 16 + rsub;
            const int row = GATHER ? ridx[mrow] : mrow;
            __builtin_amdgcn_global_load_lds(
                GLB_PTR(Ah + (size_t)row * lda + k0 + cchunk),
                LDS_PTR(sA + wave * 1024 + j * 512), 16, 0, 0);
        }
        #pragma unroll
        for (int j = 0; j < 2; ++j) {
            const int n = n0 + wave * 32 + j * 16 + rsub;
            __builtin_amdgcn_global_load_lds(
                GLB_PTR(Wh + (size_t)n * ldw + k0 + cchunk),
                LDS_PTR(sW + wave * 1024 + j * 512), 16, 0, 0);
        }
        __syncthreads();

        short8 af[4], wf[4];
        #pragma unroll
        for (int mi = 0; mi < 4; ++mi)
            af[mi] = *(const short8*)(sA + (wm * 64 + mi * 16 + lrow) * 32 + lkg * 8);
        #pragma unroll
        for (int ni = 0; ni < 4; ++ni)
            wf[ni] = *(const short8*)(sW + (wn * 64 + ni * 16 + lrow) * 32 + lkg * 8);
        #pragma unroll
        for (int mi = 0; mi < 4; ++mi)
            #pragma unroll
            for (int ni = 0; ni < 4; ++ni)
                acc[mi][ni] = __builtin_amdgcn_mfma_f32_16x16x32_bf16(af[mi], wf[ni], acc[mi][ni], 0, 0, 0);
        __syncthreads();
    }

    // epilogue: row = (lane>>4)*4 + reg, col = lane&15 (m89-verified layout)
    #pragma unroll
    for (int mi = 0; mi < 4; ++mi) {
        const int mbase = m0 + wm * 64 + mi * 16 + lkg * 4;
        #pragma unroll
        for (int ni = 0; ni < 4; ++ni) {
            const int n = n0 + wn * 64 + ni * 16 + lrow;
            if (n >= N) continue;
            const float bb = bias ? bias[n] : 0.f;
            #pragma unroll
            for (int r = 0; r < 4; ++r) {
                const int m = mbase + r;
                const float v = acc[mi][ni][r] + bb;
                if (OUT_BF16) ((unsigned short*)Cp)[(size_t)m * ldc + n] = f2bf(v);
                else          ((float*)Cp)[(size_t)m * ldc + n] = v;
            }
        }
    }
}

// ---------------------------------------------------------------------------
// Small-M sums GEMM with glds staging: part[ks][64][N] = A(64xK)@W(NxK).T
// ---------------------------------------------------------------------------
__global__ __launch_bounds__(256)
void gemm_sums_kernel(const unsigned short* __restrict__ A, int lda,
                      const unsigned short* __restrict__ W, int ldw,
                      float* __restrict__ part, int N, int Kblk)
{
    __shared__ __align__(16) unsigned short sA[64 * 32];
    __shared__ __align__(16) unsigned short sW[64 * 32];
    const int tid = threadIdx.x;
    const int n0 = blockIdx.x * 64;
    const int ks = blockIdx.y;
    const int kbeg = ks * Kblk;
    const int wave = tid >> 6, lane = tid & 63;
    const int lrow = lane & 15, lkg = lane >> 4;
    const int rsub   = lane >> 2;
    const int cchunk = (lane & 3) * 8;

    f32x4 acc[4];
    #pragma unroll
    for (int mi = 0; mi < 4; ++mi) acc[mi] = (f32x4){0.f, 0.f, 0.f, 0.f};

    for (int k0 = kbeg; k0 < kbeg + Kblk; k0 += 32) {
        __builtin_amdgcn_global_load_lds(
            GLB_PTR(A + (size_t)(wave * 16 + rsub) * lda + k0 + cchunk),
            LDS_PTR(sA + wave * 512), 16, 0, 0);
        __builtin_amdgcn_global_load_lds(
            GLB_PTR(W + (size_t)(n0 + wave * 16 + rsub) * ldw + k0 + cchunk),
            LDS_PTR(sW + wave * 512), 16, 0, 0);
        __syncthreads();
        const short8 wf = *(const short8*)(sW + (wave * 16 + lrow) * 32 + lkg * 8);
        #pragma unroll
        for (int mi = 0; mi < 4; ++mi) {
            const short8 af = *(const short8*)(sA + (mi * 16 + lrow) * 32 + lkg * 8);
            acc[mi] = __builtin_amdgcn_mfma_f32_16x16x32_bf16(af, wf, acc[mi], 0, 0, 0);
        }
        __syncthreads();
    }

    float* po = part + (size_t)ks * 64 * N;
    const int n = n0 + wave * 16 + lrow;
    #pragma unroll
    for (int mi = 0; mi < 4; ++mi)
        #pragma unroll
        for (int rr = 0; rr < 4; ++rr)
            po[(size_t)(mi * 16 + lkg * 4 + rr) * N + n] = acc[mi][rr];
}

// ---------------------------------------------------------------------------
// Step kernel (512 thr): e + softmax + l-split INTERLEAVED readout + gates.
// grid (64 b, 4 fc): same-b blocks are 64 apart in linear id -> SAME XCD
// (64 % 8 == 0), so the 4 fc-blocks share b's p_att slice in that L2.
// Thread pair (tid>>1) owns r; tid&1 = l-half.
// ---------------------------------------------------------------------------
__global__ __launch_bounds__(512)
void att_step_kernel(const float* __restrict__ part56,
                     const float* __restrict__ h2att_b,
                     const unsigned short* __restrict__ comb_bf,
                     const float* __restrict__ alpha_w,
                     const unsigned short* __restrict__ i2h_pre_bf,
                     const float* __restrict__ h2h_b,
                     float* __restrict__ cbuf,
                     unsigned short* __restrict__ h_all_bf,
                     int t)
{
    const int b = blockIdx.x, fc = blockIdx.y;
    const int tid = threadIdx.x;
    const int wave = tid >> 6, lane = tid & 63;
    __shared__ float ahT[8][64];
    __shared__ float awT[8][64];
    __shared__ float esm[kL];
    __shared__ float wsm[kL];
    __shared__ float red2[2];

    if (tid < kH) {
        const size_t base = (size_t)b * kNcat + 5 * kR + tid;
        float v = h2att_b[tid];
        #pragma unroll
        for (int s = 0; s < kKS; ++s) v += part56[(size_t)s * 64 * kNcat + base];
        ahT[tid & 7][tid >> 3] = v;
        awT[tid & 7][tid >> 3] = alpha_w[tid];
    }
    __syncthreads();

    // e: 8 waves, wave handles l = wave, wave+8, ...
    for (int l = wave; l < kL; l += 8) {
        const short8 pv = *(const short8*)(comb_bf + ((size_t)b * kL + l) * kNc2 + lane * 8);
        float a = 0.f;
        #pragma unroll
        for (int j = 0; j < 8; ++j)
            a += fast_tanh(bf2f(((const unsigned short*)&pv)[j]) + ahT[j][lane]) * awT[j][lane];
        #pragma unroll
        for (int off = 32; off; off >>= 1) a += __shfl_xor(a, off, 64);
        if (lane == 0) esm[l] = a;
    }
    __syncthreads();

    if (wave == 0) {
        float m = -1e30f;
        for (int l = lane; l < kL; l += 64) m = fmaxf(m, esm[l]);
        #pragma unroll
        for (int off = 32; off; off >>= 1) m = fmaxf(m, __shfl_xor(m, off, 64));
        float ssum = 0.f;
        for (int l = lane; l < kL; l += 64) ssum += __expf(esm[l] - m);
        #pragma unroll
        for (int off = 32; off; off >>= 1) ssum += __shfl_xor(ssum, off, 64);
        if (lane == 0) { red2[0] = m; red2[1] = 1.f / ssum; }
    }
    __syncthreads();
    if (tid < kL) wsm[tid] = __expf(esm[tid] - red2[0]) * red2[1];
    __syncthreads();

    // l-split interleaved readout: one ushort2 per l = (gate3, gate4)
    const int r = fc * 256 + (tid >> 1);
    const int l0 = (tid & 1) * 98;
    float s3 = 0.f, s4 = 0.f;
    const unsigned short* base = comb_bf + ((size_t)b * kL + l0) * kNc2 + kH + 2 * r;
    #pragma unroll 7
    for (int li = 0; li < 98; ++li) {
        const ushort2 v = *(const ushort2*)(base + (size_t)li * kNc2);
        const float wl = wsm[l0 + li];
        s3 += wl * bf2f(v.x);
        s4 += wl * bf2f(v.y);
    }
    s3 += __shfl_xor(s3, 1, 64);
    s4 += __shfl_xor(s4, 1, 64);

    if ((tid & 1) == 0) {
        const unsigned short* ib = i2h_pre_bf + (size_t)(b * kT + t) * (5 * kR);
        float S0 = bf2f(ib[r])          + h2h_b[r];
        float S1 = bf2f(ib[kR + r])     + h2h_b[kR + r];
        float S2 = bf2f(ib[2 * kR + r]) + h2h_b[2 * kR + r];
        float S3 = bf2f(ib[3 * kR + r]) + h2h_b[3 * kR + r] + s3;
        float S4 = bf2f(ib[4 * kR + r]) + h2h_b[4 * kR + r] + s4;
        #pragma unroll
        for (int s = 0; s < kKS; ++s) {
            const float* p = part56 + (size_t)s * 64 * kNcat + (size_t)b * kNcat;
            S0 += p[r];
            S1 += p[kR + r];
            S2 += p[2 * kR + r];
            S3 += p[3 * kR + r];
            S4 += p[4 * kR + r];
        }

        const float ing = fast_sig(S0);
        const float fg  = fast_sig(S1);
        const float og  = fast_sig(S2);
        const float gg  = fmaxf(S3, S4);
        const int idx = b * kR + r;
        const float nc = fg * cbuf[idx] + ing * gg;
        const float nh = og * fast_tanh(nc);
        cbuf[idx] = nc;
        h_all_bf[(size_t)(b * kT + t) * kR + r] = f2bf(nh);
    }
}

// ---------------------------------------------------------------------------
// in-place log_softmax over V; one block per row, 512 thr, float4 loads.
// ---------------------------------------------------------------------------
__global__ __launch_bounds__(512)
void log_softmax_kernel(float* __restrict__ out)
{
    __shared__ float mred[512];
    __shared__ float sred[512];
    const int tid = threadIdx.x;
    float* row = out + (size_t)blockIdx.x * kV;

    float m = -1e30f, s = 0.f;
    for (int g = tid; g < 3000; g += 512) {
        const float4 x4 = ((const float4*)row)[g];
        const float* x = (const float*)&x4;
        #pragma unroll
        for (int j = 0; j < 4; ++j) {
            const float x1 = x[j];
            if (x1 > m) { s = s * __expf(m - x1) + 1.f; m = x1; }
            else          s += __expf(x1 - m);
        }
    }
    if (tid == 0) {
        const float x1 = row[12000];
        if (x1 > m) { s = s * __expf(m - x1) + 1.f; m = x1; }
        else          s += __expf(x1 - m);
    }
    mred[tid] = m; sred[tid] = s; __syncthreads();
    for (int st = 256; st > 0; st >>= 1) {
        if (tid < st) {
            const float m2 = mred[tid + st], s2 = sred[tid + st];
            const float M = fmaxf(mred[tid], m2);
            sred[tid] = sred[tid] * __expf(mred[tid] - M) + s2 * __expf(m2 - M);
            mred[tid] = M;
        }
        __syncthreads();
    }
    const float ls = mred[0] + logf(sred[0]);
    for (int g = tid; g < 3000; g += 512) {
        float4 x4 = ((const float4*)row)[g];
        x4.x -= ls; x4.y -= ls; x4.z -= ls; x4.w -= ls;
        ((float4*)row)[g] = x4;
    }
    if (tid == 0) row[12000] -= ls;
}

extern "C" void kernel_launch(void* const* d_in, const int* in_sizes, int n_in,
                              void* d_out, int out_size, void* d_ws, size_t ws_size,
                              hipStream_t stream)
{
    const int*   seq       = (const int*)  d_in[0];
    const float* att_feats = (const float*)d_in[1];
    const float* embed_w   = (const float*)d_in[2];
    const float* ctx2att_w = (const float*)d_in[3];
    const float* ctx2att_b = (const float*)d_in[4];
    const float* h2att_w   = (const float*)d_in[5];
    const float* h2att_b   = (const float*)d_in[6];
    const float* alpha_w   = (const float*)d_in[7];
    const float* i2h_w     = (const float*)d_in[9];
    const float* i2h_b     = (const float*)d_in[10];
    const float* h2h_w     = (const float*)d_in[11];
    const float* h2h_b     = (const float*)d_in[12];
    const float* a2c_w     = (const float*)d_in[13];
    const float* a2c_b     = (const float*)d_in[14];
    const float* logit_w   = (const float*)d_in[15];
    const float* logit_b   = (const float*)d_in[16];
    float* out = (float*)d_out;

    float* ws = (float*)d_ws;
    size_t off = 0;
    auto alloc = [&](size_t nf) { float* p = ws + off; off += (nf + 3) & ~(size_t)3; return p; };

    unsigned short* af_bf      = (unsigned short*)alloc((size_t)kB * kL * kF / 2);   // 51 MB
    unsigned short* comb_bf    = (unsigned short*)alloc((size_t)kB * kL * kNc2 / 2); // 61.6 MB
    unsigned short* logit_hi   = (unsigned short*)alloc((size_t)kV * kR / 2);
    unsigned short* embed_bf   = (unsigned short*)alloc((size_t)kV * kEp / 2);
    unsigned short* i2h_bf     = (unsigned short*)alloc((size_t)5 * kR * kEp / 2);
    unsigned short* wcat_bf    = (unsigned short*)alloc((size_t)kNcat * kR / 2);     // 11.5 MB
    unsigned short* wcomb_bf   = (unsigned short*)alloc((size_t)kNc2 * kF / 2);      // 10.5 MB
    unsigned short* h_all_bf   = (unsigned short*)alloc((size_t)kB * kT * kR / 2);
    unsigned short* h_zero_bf  = (unsigned short*)alloc((size_t)kB * kR / 2);
    unsigned short* i2h_pre_bf = (unsigned short*)alloc((size_t)kB * kT * 5 * kR / 2); // 13 MB
    float* bias_comb = alloc((size_t)kNc2);
    float* part56    = alloc((size_t)kKS * kB * kNcat);  // 5.8 MB
    float* cbuf      = alloc((size_t)kB * kR);

    // all conversions + packs + zero-fills in ONE launch
    conv_all_kernel<<<4096, 256, 0, stream>>>(
        att_feats, af_bf, ctx2att_w, logit_w, logit_hi,
        h2h_w, wcat_bf, h2att_w, wcat_bf + (size_t)5 * kR * kR,
        a2c_w, wcomb_bf, embed_w, embed_bf, i2h_w, i2h_bf,
        h_zero_bf, cbuf, ctx2att_b, a2c_b, bias_comb);

    // comb = att_feats @ [ctx2att | a2c-interleaved].T + bias_comb -> bf16
    gemm_glds_kernel<true, false><<<dim3(20 * 98), 256, 0, stream>>>(
        af_bf, kF, wcomb_bf, kF, bias_comb, comb_bf, kNc2, kB * kL, kNc2, kF, nullptr,
        20, 98, 1);

    // i2h_pre = embed[seq] @ i2h_w.T + b -> bf16   (1280 x 5120, K=320 padded)
    gemm_glds_kernel<true, true><<<dim3(40 * 10), 256, 0, stream>>>(
        embed_bf, kEp, i2h_bf, kEp, i2h_b, i2h_pre_bf, 5 * kR, kB * kT, 5 * kR, kEp, seq,
        40, 10, 1);

    // 20-step recurrence: 2 launches per step
    for (int t = 0; t < kT; ++t) {
        const unsigned short* h_prev = (t == 0) ? h_zero_bf : (h_all_bf + (size_t)(t - 1) * kR);
        const int lda_h = (t == 0) ? kR : kT * kR;

        // part56 = h_prev @ [h2h | h2att].T   (64 x 5632, K=1024, ks=4)
        gemm_sums_kernel<<<dim3(kNcat / 64, kKS), 256, 0, stream>>>(
            h_prev, lda_h, wcat_bf, kR, part56, kNcat, kR / kKS);

        att_step_kernel<<<dim3(kB, 4), 512, 0, stream>>>(
            part56, h2att_b, comb_bf, alpha_w, i2h_pre_bf, h2h_b,
            cbuf, h_all_bf, t);
    }

    // logits = h_all @ logit_w.T + b -> out fp32  (1280 x 12001, K=1024)
    gemm_glds_kernel<false, false><<<dim3(94 * 10), 256, 0, stream>>>(
        h_all_bf, kR, logit_hi, kR, logit_b, out, kV, kB * kT, kV, kR, nullptr,
        94, 10, 0);

    log_softmax_kernel<<<dim3(kB * kT), 512, 0, stream>>>(out);
}